// Round 9
// baseline (111.425 us; speedup 1.0000x reference)
//
#include <hip/hip_runtime.h>

// Quantum conv circuit, 16 qubits, batch 16.
// Round 14c-resubmit (prior round hit an infra failure, kernel never ran).
// DPP reads require the SOURCE lane active. r14/r14b's xp<4/8> selected between two
// DPPs with a per-lane ternary -> each DPP ran under partial exec, partner lane
// inactive -> bound_ctrl fallback = self for every mask-4/8 gate (identical absmax
// both rounds proved direction irrelevant). Fix: issue BOTH row-shifts under full
// exec, then cndmask-select per lane.
//   mask 1/2: DPP quad_perm 0xB1/0x4E (full exec)
//   mask 4/8: row_shr:N (lane i<-i-N, bit set) + row_shl:N (i<-i+N, bit clear) + select
//   mask 16 : v_permlane16_swap; mask 32: v_permlane32_swap (both full exec)
// Base = r12 layouts (105.0us). Remaining DS in gate chain: only the 2 LDS exchanges.
// 256 blocks x 1024 threads, 4 amps/thread. st = float2[16][65536] at d_ws;
// tbl (540 floats) at d_ws + 8MB. bit p = 15-wire.
// Gate idx: L1d0(p)=15-p, L1d1(p)=16+(15-p), L2d0(p)=32+(15-p)/2, L2d1(p)=40+(15-p)/2,
//           L3d0(p)=48+(15-p)/4, L3d1(p)=52+(15-p)/4, L4d0(p)=56+(15-p)/8, L4d1=58,59.

#define DEV __device__ __forceinline__

__device__ static const unsigned char G_CP[60] = {
  15,14,13,12,11,10,9,8,7,6,5,4,3,2,1,0,
  15,14,13,12,11,10,9,8,7,6,5,4,3,2,1,0,
  15,13,11,9,7,5,3,1,
  15,13,11,9,7,5,3,1,
  15,11,7,3,
  15,11,7,3,
  15,7,
  15,7
};
__device__ static const unsigned char G_CQ[60] = {
  14,13,12,11,10,9,8,7,6,5,4,3,2,1,0,15,
  14,13,12,11,10,9,8,7,6,5,4,3,2,1,0,15,
  13,11,9,7,5,3,1,15,
  13,11,9,7,5,3,1,15,
  11,7,3,15,
  11,7,3,15,
  7,15,
  7,15
};

DEV float2 F2(float x, float y){ float2 r; r.x = x; r.y = y; return r; }
DEV float2 cmulf(float2 a, float2 b){ return F2(a.x*b.x - a.y*b.y, a.x*b.y + a.y*b.x); }
DEV int swz(int j){ return j ^ ((j>>4)&15) ^ ((j>>8)&15); }
DEV int sw2(int m){
  return m ^ ((m>>9)&1) ^ (((m>>11)&1)<<1)
           ^ ((((m>>3)&1)^((m>>8)&1))<<2)
           ^ ((((m>>4)&1)^((m>>5)&1)^((m>>10)&1))<<3);
}

// ---- VALU lane-move primitives ----
template<int C>
DEV float dppmov(float v){
  return __int_as_float(__builtin_amdgcn_update_dpp(
      __float_as_int(v), __float_as_int(v), C, 0xF, 0xF, false));
}
// partner on lane-bit MASK (1,2,4,8), full-exec only (no divergent DPP!).
// row_shr:N = receive from lane i-N; row_shl:N = receive from lane i+N.
// For MASK 4/8: issue both shifts (all USED source lanes active), select per lane.
template<int MASK>
DEV float xp(float v, int lane){
  if constexpr (MASK == 1)      return dppmov<0xB1>(v);   // quad_perm [1,0,3,2]
  else if constexpr (MASK == 2) return dppmov<0x4E>(v);   // quad_perm [2,3,0,1]
  else if constexpr (MASK == 4){
    float shr = dppmov<0x114>(v);                          // i <- i-4 (valid: bit set)
    float shl = dppmov<0x104>(v);                          // i <- i+4 (valid: bit clear)
    return (lane & 4) ? shr : shl;
  } else {
    float shr = dppmov<0x118>(v);                          // i <- i-8
    float shl = dppmov<0x108>(v);                          // i <- i+8
    return (lane & 8) ? shr : shl;
  }
}

#if __has_builtin(__builtin_amdgcn_permlane32_swap)
#define HAVE_PLS 1
// both inputs = v; out: x0 = pair element with lane-bit5=0, x1 = with bit5=1.
DEV void plswap01(float &x0, float &x1){
  auto r = __builtin_amdgcn_permlane32_swap(__float_as_uint(x0), __float_as_uint(x1), false, false);
  x0 = __uint_as_float((unsigned)r[0]);
  x1 = __uint_as_float((unsigned)r[1]);
}
#else
#define HAVE_PLS 0
#endif

#if __has_builtin(__builtin_amdgcn_permlane16_swap)
#define HAVE_PLS16 1
// swaps rows 1,3 of a with rows 0,2 of b; with a=b=v: r[0]=x0 (bit4=0), r[1]=x1.
DEV void plswap16(float &x0, float &x1){
  auto r = __builtin_amdgcn_permlane16_swap(__float_as_uint(x0), __float_as_uint(x1), false, false);
  x0 = __uint_as_float((unsigned)r[0]);
  x1 = __uint_as_float((unsigned)r[1]);
}
DEV float xp16f(float v, int lane){
  float x0 = v, x1 = v; plswap16(x0, x1);
  return (lane & 16) ? x0 : x1;
}
#else
#define HAVE_PLS16 0
DEV float xp16f(float v, int lane){ return __shfl_xor(v, 16); }
#endif

// gate on register slot bit SB
template<int SB>
DEV void gate4(float2* a, const float* __restrict__ g){
  float u00r=g[0],u00i=g[1],u01r=g[2],u01i=g[3],u10r=g[4],u10i=g[5],u11r=g[6],u11i=g[7];
  #pragma unroll
  for (int m=0;m<2;m++){
    int i0 = (SB==0) ? (m<<1) : m;
    int i1 = i0 | (1<<SB);
    float2 x0=a[i0], x1=a[i1];
    a[i0] = F2(u00r*x0.x - u00i*x0.y + u01r*x1.x - u01i*x1.y,
               u00r*x0.y + u00i*x0.x + u01r*x1.y + u01i*x1.x);
    a[i1] = F2(u10r*x0.x - u10i*x0.y + u11r*x1.x - u11i*x1.y,
               u10r*x0.y + u10i*x0.x + u11r*x1.y + u11i*x1.x);
  }
}

// lane-bit gate (MASK in {1,2,4,8}; DPP partner): new = A*self + B*partner.
template<int MASK>
DEV void lgateX(float2* a, const float* __restrict__ g, int lane){
  bool h = (lane & MASK) != 0;
  float Ar = h ? g[6] : g[0], Ai = h ? g[7] : g[1];
  float Br = h ? g[4] : g[2], Bi = h ? g[5] : g[3];
  #pragma unroll
  for (int s=0;s<4;s++){
    float px = xp<MASK>(a[s].x, lane);
    float py = xp<MASK>(a[s].y, lane);
    a[s] = F2(Ar*a[s].x - Ai*a[s].y + Br*px - Bi*py,
              Ar*a[s].y + Ai*a[s].x + Br*py + Bi*px);
  }
}

// generic shfl lane gate (fallback only)
DEV void lgate(float2* a, const float* __restrict__ g, int mask, int lane){
  bool h = (lane & mask) != 0;
  float Ar = h ? g[6] : g[0], Ai = h ? g[7] : g[1];
  float Br = h ? g[4] : g[2], Bi = h ? g[5] : g[3];
  #pragma unroll
  for (int s=0;s<4;s++){
    float px = __shfl_xor(a[s].x, mask);
    float py = __shfl_xor(a[s].y, mask);
    a[s] = F2(Ar*a[s].x - Ai*a[s].y + Br*px - Bi*py,
              Ar*a[s].y + Ai*a[s].x + Br*py + Bi*px);
  }
}

// mask-16 lane gate via permlane16_swap: h=0 -> u00*x0+u01*x1; h=1 -> u10*x0+u11*x1.
DEV void lgate16(float2* a, const float* __restrict__ g, int lane){
#if HAVE_PLS16
  bool h = (lane & 16) != 0;
  float c0r = h ? g[4] : g[0], c0i = h ? g[5] : g[1];
  float c1r = h ? g[6] : g[2], c1i = h ? g[7] : g[3];
  #pragma unroll
  for (int s=0;s<4;s++){
    float x0x = a[s].x, x1x = a[s].x, x0y = a[s].y, x1y = a[s].y;
    plswap16(x0x, x1x); plswap16(x0y, x1y);
    a[s] = F2(c0r*x0x - c0i*x0y + c1r*x1x - c1i*x1y,
              c0r*x0y + c0i*x0x + c1r*x1y + c1i*x1x);
  }
#else
  lgate(a, g, 16, lane);
#endif
}

// mask-32 lane gate via permlane32_swap
DEV void lgate32(float2* a, const float* __restrict__ g, int lane){
#if HAVE_PLS
  bool h = (lane & 32) != 0;
  float c0r = h ? g[4] : g[0], c0i = h ? g[5] : g[1];
  float c1r = h ? g[6] : g[2], c1i = h ? g[7] : g[3];
  #pragma unroll
  for (int s=0;s<4;s++){
    float x0x = a[s].x, x1x = a[s].x, x0y = a[s].y, x1y = a[s].y;
    plswap01(x0x, x1x); plswap01(x0y, x1y);
    a[s] = F2(c0r*x0x - c0i*x0y + c1r*x1x - c1i*x1y,
              c0r*x0y + c0i*x0x + c1r*x1y + c1i*x1x);
  }
#else
  lgate(a, g, 32, lane);
#endif
}

// CNOT: ctrl lane-bit CMASK, tgt lane-bit TMASK in {1,2,4,8}.
// xp is evaluated UNCONDITIONALLY (full exec); only the select is predicated.
template<int CMASK,int TMASK>
DEV void cswapX(float2* a, int lane){
  bool c = (lane & CMASK) != 0;
  #pragma unroll
  for (int s=0;s<4;s++){
    float px = xp<TMASK>(a[s].x, lane);
    float py = xp<TMASK>(a[s].y, lane);
    a[s].x = c ? px : a[s].x;
    a[s].y = c ? py : a[s].y;
  }
}
// CNOT ctrl CMASK, tgt = lane bit 16 (permlane16 partner)
template<int CMASK>
DEV void cswapT16(float2* a, int lane){
  bool c = (lane & CMASK) != 0;
  #pragma unroll
  for (int s=0;s<4;s++){
    float px = xp16f(a[s].x, lane);
    float py = xp16f(a[s].y, lane);
    a[s].x = c ? px : a[s].x;
    a[s].y = c ? py : a[s].y;
  }
}
// CNOT ctrl CMASK, tgt = lane bit 8 (DPP row-shift partner)
template<int CMASK>
DEV void cswapT8(float2* a, int lane){
  bool c = (lane & CMASK) != 0;
  #pragma unroll
  for (int s=0;s<4;s++){
    float px = xp<8>(a[s].x, lane);
    float py = xp<8>(a[s].y, lane);
    a[s].x = c ? px : a[s].x;
    a[s].y = c ? py : a[s].y;
  }
}

// RZZ: couplings [C0,C0+N0) u [C1,C1+N1). hh[k] = theta3(k)/2; Ib = index, reg bits 0.
template<int C0,int N0,int C1,int N1,unsigned M0,unsigned M1>
DEV void diagx(float2* a, const float* __restrict__ hh, unsigned Ib){
  const unsigned rm = M0|M1;
  float base = 0.f;
  #pragma unroll
  for (int k=C0;k<C0+N0;k++){
    const int p=G_CP[k], q=G_CQ[k];
    if (!(((1u<<p)|(1u<<q)) & rm)){
      float h = hh[k];
      base += (((Ib>>p)^(Ib>>q))&1u) ? h : -h;
    }
  }
  #pragma unroll
  for (int k=C1;k<C1+N1;k++){
    const int p=G_CP[k], q=G_CQ[k];
    if (!(((1u<<p)|(1u<<q)) & rm)){
      float h = hh[k];
      base += (((Ib>>p)^(Ib>>q))&1u) ? h : -h;
    }
  }
  #pragma unroll
  for (int r=0;r<4;r++){
    unsigned Ir = Ib ^ ((r&1)?M0:0u) ^ ((r&2)?M1:0u);
    float ph = base;
    #pragma unroll
    for (int k=C0;k<C0+N0;k++){
      const int p=G_CP[k], q=G_CQ[k];
      if (((1u<<p)|(1u<<q)) & rm){
        float h = hh[k];
        ph += (((Ir>>p)^(Ir>>q))&1u) ? h : -h;
      }
    }
    #pragma unroll
    for (int k=C1;k<C1+N1;k++){
      const int p=G_CP[k], q=G_CQ[k];
      if (((1u<<p)|(1u<<q)) & rm){
        float h = hh[k];
        ph += (((Ir>>p)^(Ir>>q))&1u) ? h : -h;
      }
    }
    float c, s;
    __sincosf(ph, &s, &c);
    a[r] = cmulf(a[r], F2(c, s));
  }
}

// ---- per-block gate-table build (f32) ----
DEV void build_entry(float* sh, const float* __restrict__ p0, const float* __restrict__ p1,
                     const float* __restrict__ p2, const float* __restrict__ p3, int g){
  int d, j, n; const float* P;
  if (g < 32)      { n=16; d=(g>>4)&1; j=g&15; P=p0; }
  else if (g < 48) { n=8;  d=(g>>3)&1; j=g&7;  P=p1; }
  else if (g < 56) { n=4;  d=(g>>2)&1; j=g&3;  P=p2; }
  else             { n=2;  d=(g>>1)&1; j=g&1;  P=p3; }
  int base = 4*j + 4*n*d;
  float th0 = P[base+0], th1 = P[base+1], th2 = P[base+2], th3 = P[base+3];
  float c0,s0,ca,sa,c2,s2;
  sincosf(0.5f*th0, &s0, &c0);
  sincosf(0.5f*th1, &sa, &ca);
  sincosf(0.5f*th2, &s2, &c2);
  float B00r =  ca*c0, B00i = -sa*c0;
  float B01r = -sa*s0, B01i = -ca*s0;
  float B10r =  sa*s0, B10i = -ca*s0;
  float B11r =  ca*c0, B11i =  sa*c0;
  float* o8 = sh + g*8;
  o8[0]=c2*B00r + s2*B10i; o8[1]=c2*B00i - s2*B10r;
  o8[2]=c2*B01r + s2*B11i; o8[3]=c2*B01i - s2*B11r;
  o8[4]=s2*B00i + c2*B10r; o8[5]=-s2*B00r + c2*B10i;
  o8[6]=s2*B01i + c2*B11r; o8[7]=-s2*B01r + c2*B11i;
  sh[480 + g] = 0.5f*th3;
}

// ======== pass A: tile j = b0..b11 (identity), outer o = b12..b15 ========
// Layout A: reg=(b0,b1), lane=(b2..b7), wave=(b8..b11)  [j = (t<<2)|s]
// Layout B: reg=(b10,b11), lane=(b8,b9,b6,b7,b4,b5), wave=(b0..b3)
// Store: addr = (batch<<16)|(o<<12)|(wv<<8)|(lane<<2)|s  (linear, wave-contiguous 2KB)
__global__ __launch_bounds__(1024, 4)
void k_pa(const float* __restrict__ xre, const float* __restrict__ xim,
          const float* __restrict__ pp0, const float* __restrict__ pp1,
          const float* __restrict__ pp2, const float* __restrict__ pp3,
          float* __restrict__ tbl, float2* __restrict__ st, float* __restrict__ out){
  const int t = threadIdx.x, lane = t & 63, wv = t >> 6;   // wv 0..15
  const int batch = blockIdx.x >> 4, o = blockIdx.x & 15;
  const unsigned hi = ((unsigned)batch<<16) | ((unsigned)o<<12);
  __shared__ float2 lds[4096];
  __shared__ float sh[544];
  float2 a[4];
  { // load layout A (contiguous; issues before table build)
    unsigned base = hi | ((unsigned)t<<2);
    float4 re = *(const float4*)(xre + base);
    float4 im = *(const float4*)(xim + base);
    a[0]=F2(re.x,im.x); a[1]=F2(re.y,im.y); a[2]=F2(re.z,im.z); a[3]=F2(re.w,im.w);
  }
  if (t < 60) build_entry(sh, pp0, pp1, pp2, pp3, t);
  if (blockIdx.x == 0 && t >= 64 && t < 80) out[t - 64] = 0.f;
  __syncthreads();
  if (blockIdx.x == 0){
    for (int i = t; i < 540; i += 1024) tbl[i] = sh[i];
  }
  #define LTB(i) (sh + (i)*8)
  const float* HH = sh + 480;
  // ---- layout A ----
  gate4<0>(a, LTB(15)); gate4<1>(a, LTB(14));                    // L1d0 b0,b1
  lgateX<1>(a, LTB(13), lane); lgateX<2>(a, LTB(12), lane);      // b2,b3
  lgateX<4>(a, LTB(11), lane); lgateX<8>(a, LTB(10), lane);      // b4,b5
  lgate16(a, LTB(9), lane);    lgate32(a, LTB(8), lane);         // b6,b7
  const unsigned IbA = ((unsigned)o<<12) | ((unsigned)wv<<8) | ((unsigned)lane<<2);
  diagx<8,7,0,0,1u,2u>(a, HH, IbA);                              // D0 (7,6)..(1,0)
  gate4<1>(a, LTB(30));                                          // L1d1 b1
  lgateX<1>(a, LTB(29), lane); lgateX<2>(a, LTB(28), lane);      // b2,b3
  lgateX<4>(a, LTB(27), lane); lgateX<8>(a, LTB(26), lane);      // b4,b5
  lgate16(a, LTB(25), lane);                                     // b6
  diagx<25,5,0,0,1u,2u>(a, HH, IbA);                             // D1 (6,5)..(2,1)
  cswapX<2,1>(a, lane);                                          // CNOT 3->2
  cswapX<8,4>(a, lane);                                          // CNOT 5->4
  // ---- exchange ----
  #pragma unroll
  for (int s=0;s<4;s++) lds[swz((t<<2)|s)] = a[s];
  __syncthreads();
  const int idxR = (wv&15) | (((lane>>4)&1)<<4) | (((lane>>5)&1)<<5)
                 | (((lane>>2)&1)<<6) | (((lane>>3)&1)<<7)
                 | ((lane&1)<<8) | (((lane>>1)&1)<<9);
  #pragma unroll
  for (int s=0;s<4;s++) a[s] = lds[swz(idxR | ((s&1)<<10) | (((s>>1)&1)<<11))];
  // ---- layout B: lane=(b8:1, b9:2, b6:4, b7:8, b4:16, b5:32) ----
  lgateX<1>(a, LTB(7), lane); lgateX<2>(a, LTB(6), lane);        // L1d0 b8,b9
  gate4<0>(a, LTB(5)); gate4<1>(a, LTB(4));                      // L1d0 b10,b11
  const unsigned IbB = ((unsigned)o<<12) | (unsigned)idxR;
  diagx<4,4,0,0,1024u,2048u>(a, HH, IbB);                        // D0 (11,10)..(8,7)
  lgateX<8>(a, LTB(24), lane);                                   // L1d1 b7
  lgateX<1>(a, LTB(23), lane); lgateX<2>(a, LTB(22), lane);      // L1d1 b8,b9
  gate4<0>(a, LTB(21));                                          // L1d1 b10
  diagx<21,4,0,0,1024u,2048u>(a, HH, IbB);                       // D1 (10,9)..(7,6)
  cswapX<8,4>(a, lane);                                          // CNOT 7->6
  cswapX<2,1>(a, lane);                                          // CNOT 9->8
  {
    unsigned sb = hi | ((unsigned)wv<<8) | ((unsigned)lane<<2);
    float4 v0, v1;
    v0.x=a[0].x; v0.y=a[0].y; v0.z=a[1].x; v0.w=a[1].y;
    v1.x=a[2].x; v1.y=a[2].y; v1.z=a[3].x; v1.w=a[3].y;
    *(float4*)(st + sb) = v0;
    *(float4*)(st + sb + 2) = v1;
  }
  #undef LTB
}

#define TBL(i) (tbl + (i)*8)

// ======== pass B: tile m: m0..m11 -> b{0,1,3,5,7,9,10,11,12,13,14,15}; outer b{2,4,6,8}
// Layout A: reg=(b10,b11); lane=(b12:1,b13:2,b14:4,b15:8,b0:16,b1:32); wave=(b3,b5,b7,b9)
// Layout B: reg=(b1,b3); lane=(b5:1,b7:2,b9:4,b11:8,b13:16,b15:32); wave=(b0,b10,b12,b14)
__global__ __launch_bounds__(1024, 4)
void k_pb(const float* __restrict__ tbl, float2* __restrict__ st, float* __restrict__ out){
  const int t = threadIdx.x, lane = t & 63, wv = t >> 6;
  const int batch = blockIdx.x >> 4, o = blockIdx.x & 15;
  __shared__ float2 lds[4096];
  __shared__ float red[16];
  const float* HH = tbl + 480;
  const unsigned opart = ((unsigned)(o&1)<<2) | ((unsigned)((o>>1)&1)<<4)
                       | ((unsigned)((o>>2)&1)<<6) | ((unsigned)((o>>3)&1)<<8);
  float2 a[4];
  { // gather: inverse of pass-A store permutation; 32B contiguous per thread
    unsigned gb = ((unsigned)batch<<16)
      | (((unsigned)(o>>3)&1)<<2) | (((unsigned)(o>>2)&1)<<4)
      | (((unsigned)(o>>1)&1)<<6) | (((unsigned)o&1)<<10)
      | (((unsigned)(wv>>3)&1)<<3) | (((unsigned)(wv>>2)&1)<<5)
      | (((unsigned)(wv>>1)&1)<<7) | (((unsigned)wv&1)<<11)
      | (((unsigned)(lane>>4)&1)<<8) | (((unsigned)(lane>>5)&1)<<9)
      | (((unsigned)lane&1)<<12) | (((unsigned)(lane>>1)&1)<<13)
      | (((unsigned)(lane>>2)&1)<<14) | (((unsigned)(lane>>3)&1)<<15);
    const float4* sp = (const float4*)(st + gb);
    float4 lo = sp[0], hi4 = sp[1];
    a[0]=F2(lo.x,lo.y); a[1]=F2(lo.z,lo.w); a[2]=F2(hi4.x,hi4.y); a[3]=F2(hi4.z,hi4.w);
  }
  const unsigned IbA = opart
    | (((unsigned)lane&1)<<12) | (((unsigned)(lane>>1)&1)<<13)
    | (((unsigned)(lane>>2)&1)<<14) | (((unsigned)(lane>>3)&1)<<15)
    | (((unsigned)(lane>>4)&1)<<0) | (((unsigned)(lane>>5)&1)<<1)
    | (((unsigned)wv&1)<<3) | (((unsigned)(wv>>1)&1)<<5)
    | (((unsigned)(wv>>2)&1)<<7) | (((unsigned)(wv>>3)&1)<<9);
  // ---- layout A ----
  lgateX<1>(a, TBL(3), lane); lgateX<2>(a, TBL(2), lane);        // L1d0 b12,b13
  lgateX<4>(a, TBL(1), lane); lgateX<8>(a, TBL(0), lane);        // b14,b15
  diagx<0,4,15,1,1024u,2048u>(a, HH, IbA);                       // D0 k0..3,k15
  lgate16(a, TBL(31), lane);                                     // L1d1 b0
  gate4<1>(a, TBL(20));                                          // L1d1 b11
  lgateX<1>(a, TBL(19), lane); lgateX<2>(a, TBL(18), lane);      // b12,b13
  lgateX<4>(a, TBL(17), lane); lgateX<8>(a, TBL(16), lane);      // b14,b15
  diagx<16,5,30,2,1024u,2048u>(a, HH, IbA);                      // D1 k16..20,k30,k31
  cswapX<8,4>(a, lane);                                          // CNOT 15->14
  cswapX<2,1>(a, lane);                                          // CNOT 13->12
  cswapT16<32>(a, lane);                                         // CNOT 1->0
  { float2 tmp=a[2]; a[2]=a[3]; a[3]=tmp; }                      // CNOT 11->10 (reg)
  // ---- exchange ----
  const int idxW = ((lane>>4)&1) | (((lane>>5)&1)<<1)
                 | ((wv&1)<<2) | (((wv>>1)&1)<<3) | (((wv>>2)&1)<<4) | (((wv>>3)&1)<<5)
                 | ((lane&1)<<8) | (((lane>>1)&1)<<9)
                 | (((lane>>2)&1)<<10) | (((lane>>3)&1)<<11);
  #pragma unroll
  for (int s=0;s<4;s++) lds[sw2(idxW | ((s&1)<<6) | (((s>>1)&1)<<7))] = a[s];
  __syncthreads();
  const int idxR = (wv&1) | (((wv>>1)&1)<<6) | (((wv>>2)&1)<<8) | (((wv>>3)&1)<<10)
                 | ((lane&1)<<3) | (((lane>>1)&1)<<4) | (((lane>>2)&1)<<5)
                 | (((lane>>3)&1)<<7) | (((lane>>4)&1)<<9) | (((lane>>5)&1)<<11);
  #pragma unroll
  for (int s=0;s<4;s++) a[s] = lds[sw2(idxR | ((s&1)<<1) | (((s>>1)&1)<<2))];
  // ---- layout B ----
  const unsigned IbB = opart
    | (((unsigned)wv&1)<<0) | (((unsigned)(wv>>1)&1)<<10)
    | (((unsigned)(wv>>2)&1)<<12) | (((unsigned)(wv>>3)&1)<<14)
    | (((unsigned)lane&1)<<5) | (((unsigned)(lane>>1)&1)<<7)
    | (((unsigned)(lane>>2)&1)<<9) | (((unsigned)(lane>>3)&1)<<11)
    | (((unsigned)(lane>>4)&1)<<13) | (((unsigned)(lane>>5)&1)<<15);
  // L2d0
  gate4<0>(a, TBL(39)); gate4<1>(a, TBL(38));
  lgateX<1>(a, TBL(37), lane); lgateX<2>(a, TBL(36), lane); lgateX<4>(a, TBL(35), lane);
  lgateX<8>(a, TBL(34), lane); lgate16(a, TBL(33), lane); lgate32(a, TBL(32), lane);
  diagx<32,8,0,0,2u,8u>(a, HH, IbB);
  // L2d1
  gate4<0>(a, TBL(47)); gate4<1>(a, TBL(46));
  lgateX<1>(a, TBL(45), lane); lgateX<2>(a, TBL(44), lane); lgateX<4>(a, TBL(43), lane);
  lgateX<8>(a, TBL(42), lane); lgate16(a, TBL(41), lane); lgate32(a, TBL(40), lane);
  diagx<40,8,0,0,2u,8u>(a, HH, IbB);
  // sigma2: (b15->b13),(b11->b9),(b7->b5) lane; (b3->b1) reg
  cswapT16<32>(a, lane); cswapX<8,4>(a, lane); cswapX<2,1>(a, lane);
  { float2 tmp=a[2]; a[2]=a[3]; a[3]=tmp; }
  // L3d0 {b15,b11,b7,b3}
  lgate32(a, TBL(48), lane); lgateX<8>(a, TBL(49), lane); lgateX<2>(a, TBL(50), lane);
  gate4<1>(a, TBL(51));
  diagx<48,4,0,0,2u,8u>(a, HH, IbB);
  // L3d1
  lgate32(a, TBL(52), lane); lgateX<8>(a, TBL(53), lane); lgateX<2>(a, TBL(54), lane);
  gate4<1>(a, TBL(55));
  diagx<52,4,0,0,2u,8u>(a, HH, IbB);
  // sigma3: (b15->b11) lane (ctrl 32, tgt 8); (b7->b3): ctrl lane bit1, tgt reg s1
  cswapT8<32>(a, lane);
  if (lane & 2){
    float2 t0=a[0]; a[0]=a[2]; a[2]=t0;
    float2 t1=a[1]; a[1]=a[3]; a[3]=t1;
  }
  // L4d0 {b15,b7}, D4_0, L4d1 b15
  lgate32(a, TBL(56), lane); lgateX<2>(a, TBL(57), lane);
  diagx<56,2,0,0,2u,8u>(a, HH, IbB);
  lgate32(a, TBL(58), lane);
  // measure Z on b15 = lane bit5
  float sl = 0.f;
  #pragma unroll
  for (int s=0;s<4;s++) sl += a[s].x*a[s].x + a[s].y*a[s].y;
  float sg = (lane & 32) ? -sl : sl;
  #pragma unroll
  for (int off=32; off>0; off>>=1) sg += __shfl_down(sg, off);
  if ((t & 63) == 0) red[wv] = sg;
  __syncthreads();
  if (t == 0){
    float tot = 0.f;
    #pragma unroll
    for (int w=0; w<16; w++) tot += red[w];
    atomicAdd(out + batch, tot);
  }
}

extern "C" void kernel_launch(void* const* d_in, const int* in_sizes, int n_in,
                              void* d_out, int out_size, void* d_ws, size_t ws_size,
                              hipStream_t stream) {
  const float* xre = (const float*)d_in[0];
  const float* xim = (const float*)d_in[1];
  const float* p0  = (const float*)d_in[2];
  const float* p1  = (const float*)d_in[3];
  const float* p2  = (const float*)d_in[4];
  const float* p3  = (const float*)d_in[5];
  float* out = (float*)d_out;
  float2* st = (float2*)d_ws;                           // 8 MB state
  float* tbl = (float*)((char*)d_ws + (8u<<20));        // 540-float gate table

  k_pa<<<256, 1024, 0, stream>>>(xre, xim, p0, p1, p2, p3, tbl, st, out);
  k_pb<<<256, 1024, 0, stream>>>(tbl, st, out);
}

// Round 10
// 105.622 us; speedup vs baseline: 1.0549x; 1.0549x over previous
//
#include <hip/hip_runtime.h>

// Quantum conv circuit, 16 qubits, batch 16.
// Round 15: VALU-count cuts on the r12 base (105.0us best). r13/r14 lesson:
// DS shuffles co-issue with VALU and are already hidden; kernels are VALU-bound.
//  - table re-layout [u00,u01|u11,u10]: lgate coef = 1 ds_read_b128 at g+(h?4:0)
//    (was 8 loads + 4 cndmask); gate4/lgate32 = 2x b128.
//  - pass B stages the table into LDS (overlapped with gather) -> same path.
//  - diag: ONE sincos per round (base angle), reg couplings applied as exact
//    cmuls with tabulated (cos h, sin h). -36 sincos/thread.
// Shuffles/layouts/index maps verbatim r12 (shfl_xor + permlane32 for mask-32).
// 256 blocks x 1024 threads, 4 amps/thread. st = float2[16][65536] at d_ws;
// tbl (664 floats) at d_ws + 8MB. bit p = 15-wire.
// Gate idx: L1d0(p)=15-p, L1d1(p)=16+(15-p), L2d0(p)=32+(15-p)/2, L2d1(p)=40+(15-p)/2,
//           L3d0(p)=48+(15-p)/4, L3d1(p)=52+(15-p)/4, L4d0(p)=56+(15-p)/8, L4d1=58,59.
// Table entry g (8 floats): [u00r,u00i,u01r,u01i, u11r,u11i,u10r,u10i]
// hh[k]=theta3/2 at 480+k; cs[k]=(cos,sin) at 544+2k.

#define DEV __device__ __forceinline__

__device__ static const unsigned char G_CP[60] = {
  15,14,13,12,11,10,9,8,7,6,5,4,3,2,1,0,
  15,14,13,12,11,10,9,8,7,6,5,4,3,2,1,0,
  15,13,11,9,7,5,3,1,
  15,13,11,9,7,5,3,1,
  15,11,7,3,
  15,11,7,3,
  15,7,
  15,7
};
__device__ static const unsigned char G_CQ[60] = {
  14,13,12,11,10,9,8,7,6,5,4,3,2,1,0,15,
  14,13,12,11,10,9,8,7,6,5,4,3,2,1,0,15,
  13,11,9,7,5,3,1,15,
  13,11,9,7,5,3,1,15,
  11,7,3,15,
  11,7,3,15,
  7,15,
  7,15
};

DEV float2 F2(float x, float y){ float2 r; r.x = x; r.y = y; return r; }
DEV float2 cmulf(float2 a, float2 b){ return F2(a.x*b.x - a.y*b.y, a.x*b.y + a.y*b.x); }
DEV int swz(int j){ return j ^ ((j>>4)&15) ^ ((j>>8)&15); }
DEV int sw2(int m){
  return m ^ ((m>>9)&1) ^ (((m>>11)&1)<<1)
           ^ ((((m>>3)&1)^((m>>8)&1))<<2)
           ^ ((((m>>4)&1)^((m>>5)&1)^((m>>10)&1))<<3);
}

#if __has_builtin(__builtin_amdgcn_permlane32_swap)
#define HAVE_PLS 1
// both inputs = v; out: x0 = pair element with lane-bit5=0, x1 = with bit5=1.
DEV void plswap01(float &x0, float &x1){
  auto r = __builtin_amdgcn_permlane32_swap(__float_as_uint(x0), __float_as_uint(x1), false, false);
  x0 = __uint_as_float((unsigned)r[0]);
  x1 = __uint_as_float((unsigned)r[1]);
}
#else
#define HAVE_PLS 0
#endif

// gate on register slot bit SB. Entry: lo=(u00,u01), hi=(u11,u10).
template<int SB>
DEV void gate4(float2* a, const float* __restrict__ g){
  const float4 lo = *(const float4*)g;
  const float4 hi = *(const float4*)(g + 4);
  float u00r=lo.x,u00i=lo.y,u01r=lo.z,u01i=lo.w;
  float u11r=hi.x,u11i=hi.y,u10r=hi.z,u10i=hi.w;
  #pragma unroll
  for (int m=0;m<2;m++){
    int i0 = (SB==0) ? (m<<1) : m;
    int i1 = i0 | (1<<SB);
    float2 x0=a[i0], x1=a[i1];
    a[i0] = F2(u00r*x0.x - u00i*x0.y + u01r*x1.x - u01i*x1.y,
               u00r*x0.y + u00i*x0.x + u01r*x1.y + u01i*x1.x);
    a[i1] = F2(u10r*x0.x - u10i*x0.y + u11r*x1.x - u11i*x1.y,
               u10r*x0.y + u10i*x0.x + u11r*x1.y + u11i*x1.x);
  }
}

// lane-bit gate: new = A*self + B*partner; (A,B) = one float4 at g + (h?4:0).
DEV void lgate(float2* a, const float* __restrict__ g, int mask, int lane){
  const float4 cf = *(const float4*)(g + ((lane & mask) ? 4 : 0));
  float Ar=cf.x, Ai=cf.y, Br=cf.z, Bi=cf.w;
  #pragma unroll
  for (int s=0;s<4;s++){
    float px = __shfl_xor(a[s].x, mask);
    float py = __shfl_xor(a[s].y, mask);
    a[s] = F2(Ar*a[s].x - Ai*a[s].y + Br*px - Bi*py,
              Ar*a[s].y + Ai*a[s].x + Br*py + Bi*px);
  }
}

// mask-32 lane gate via permlane32_swap: h=0 -> u00*x0+u01*x1; h=1 -> u10*x0+u11*x1.
// cf at (h?4:0) = (A,B); c0 (mult x0) = h? B:A, c1 (mult x1) = h? A:B.
DEV void lgate32(float2* a, const float* __restrict__ g, int lane){
#if HAVE_PLS
  bool h = (lane & 32) != 0;
  const float4 cf = *(const float4*)(g + (h ? 4 : 0));
  float c0r = h ? cf.z : cf.x, c0i = h ? cf.w : cf.y;
  float c1r = h ? cf.x : cf.z, c1i = h ? cf.y : cf.w;
  #pragma unroll
  for (int s=0;s<4;s++){
    float x0x = a[s].x, x1x = a[s].x, x0y = a[s].y, x1y = a[s].y;
    plswap01(x0x, x1x); plswap01(x0y, x1y);
    a[s] = F2(c0r*x0x - c0i*x0y + c1r*x1x - c1i*x1y,
              c0r*x0y + c0i*x0x + c1r*x1y + c1i*x1x);
  }
#else
  lgate(a, g, 32, lane);
#endif
}

// CNOT ctrl lane-bit cmask, tgt lane-bit tmask (shfl_xor + predicated copy)
DEV void cswap(float2* a, int cmask, int tmask, int lane){
  bool c = (lane & cmask) != 0;
  #pragma unroll
  for (int s=0;s<4;s++){
    float px = __shfl_xor(a[s].x, tmask);
    float py = __shfl_xor(a[s].y, tmask);
    if (c){ a[s].x = px; a[s].y = py; }
  }
}

// RZZ round, couplings [C0,C0+N0) u [C1,C1+N1). hh[k]=theta3/2, cs[k]=(cos,sin).
// base = sum over non-reg couplings (one sincos); reg couplings applied per slot
// as exact cmuls with (ck, +-sk). Ib = index with reg bits zeroed.
template<int C0,int N0,int C1,int N1,unsigned M0,unsigned M1>
DEV void diagv(float2* a, const float* __restrict__ hh, const float* __restrict__ cs, unsigned Ib){
  const unsigned rm = M0|M1;
  float b0 = 0.f, b1 = 0.f;
  #pragma unroll
  for (int k=C0;k<C0+N0;k++){
    const int p=G_CP[k], q=G_CQ[k];
    if (!(((1u<<p)|(1u<<q)) & rm)){
      float h = hh[k];
      float v = (((Ib>>p)^(Ib>>q))&1u) ? h : -h;
      if (k & 1) b1 += v; else b0 += v;
    }
  }
  #pragma unroll
  for (int k=C1;k<C1+N1;k++){
    const int p=G_CP[k], q=G_CQ[k];
    if (!(((1u<<p)|(1u<<q)) & rm)){
      float h = hh[k];
      float v = (((Ib>>p)^(Ib>>q))&1u) ? h : -h;
      if (k & 1) b1 += v; else b0 += v;
    }
  }
  float cb, sb;
  __sincosf(b0 + b1, &sb, &cb);
  #pragma unroll
  for (int r=0;r<4;r++){
    unsigned Ir = Ib ^ ((r&1)?M0:0u) ^ ((r&2)?M1:0u);
    float Fr = cb, Fi = sb;
    #pragma unroll
    for (int k=C0;k<C0+N0;k++){
      const int p=G_CP[k], q=G_CQ[k];
      if (((1u<<p)|(1u<<q)) & rm){
        float ck = cs[2*k], sk = cs[2*k+1];
        float ss = (((Ir>>p)^(Ir>>q))&1u) ? sk : -sk;
        float nr = Fr*ck - Fi*ss, ni = Fr*ss + Fi*ck;
        Fr = nr; Fi = ni;
      }
    }
    #pragma unroll
    for (int k=C1;k<C1+N1;k++){
      const int p=G_CP[k], q=G_CQ[k];
      if (((1u<<p)|(1u<<q)) & rm){
        float ck = cs[2*k], sk = cs[2*k+1];
        float ss = (((Ir>>p)^(Ir>>q))&1u) ? sk : -sk;
        float nr = Fr*ck - Fi*ss, ni = Fr*ss + Fi*ck;
        Fr = nr; Fi = ni;
      }
    }
    a[r] = cmulf(a[r], F2(Fr, Fi));
  }
}

// ---- per-block gate-table build (f32). New layout: [u00,u01 | u11,u10];
// hh at 480+g; cs at 544+2g. ----
DEV void build_entry(float* sh, const float* __restrict__ p0, const float* __restrict__ p1,
                     const float* __restrict__ p2, const float* __restrict__ p3, int g){
  int d, j, n; const float* P;
  if (g < 32)      { n=16; d=(g>>4)&1; j=g&15; P=p0; }
  else if (g < 48) { n=8;  d=(g>>3)&1; j=g&7;  P=p1; }
  else if (g < 56) { n=4;  d=(g>>2)&1; j=g&3;  P=p2; }
  else             { n=2;  d=(g>>1)&1; j=g&1;  P=p3; }
  int base = 4*j + 4*n*d;
  float th0 = P[base+0], th1 = P[base+1], th2 = P[base+2], th3 = P[base+3];
  float c0,s0,ca,sa,c2,s2;
  sincosf(0.5f*th0, &s0, &c0);
  sincosf(0.5f*th1, &sa, &ca);
  sincosf(0.5f*th2, &s2, &c2);
  float B00r =  ca*c0, B00i = -sa*c0;
  float B01r = -sa*s0, B01i = -ca*s0;
  float B10r =  sa*s0, B10i = -ca*s0;
  float B11r =  ca*c0, B11i =  sa*c0;
  float* o8 = sh + g*8;
  o8[0]=c2*B00r + s2*B10i; o8[1]=c2*B00i - s2*B10r;      // u00
  o8[2]=c2*B01r + s2*B11i; o8[3]=c2*B01i - s2*B11r;      // u01
  o8[4]=s2*B01i + c2*B11r; o8[5]=-s2*B01r + c2*B11i;     // u11
  o8[6]=s2*B00i + c2*B10r; o8[7]=-s2*B00r + c2*B10i;     // u10
  sh[480 + g] = 0.5f*th3;
  float ch, shn;
  sincosf(0.5f*th3, &shn, &ch);
  sh[544 + 2*g]     = ch;
  sh[544 + 2*g + 1] = shn;
}

// ======== pass A: tile j = b0..b11 (identity), outer o = b12..b15 ========
// Layout A: reg=(b0,b1), lane=(b2..b7), wave=(b8..b11)  [j = (t<<2)|s]
// Layout B: reg=(b10,b11), lane=(b8,b9,b6,b7,b4,b5), wave=(b0..b3)
// Store: addr = (batch<<16)|(o<<12)|(wv<<8)|(lane<<2)|s  (linear, wave-contiguous 2KB)
__global__ __launch_bounds__(1024, 4)
void k_pa(const float* __restrict__ xre, const float* __restrict__ xim,
          const float* __restrict__ pp0, const float* __restrict__ pp1,
          const float* __restrict__ pp2, const float* __restrict__ pp3,
          float* __restrict__ tbl, float2* __restrict__ st, float* __restrict__ out){
  const int t = threadIdx.x, lane = t & 63, wv = t >> 6;   // wv 0..15
  const int batch = blockIdx.x >> 4, o = blockIdx.x & 15;
  const unsigned hi = ((unsigned)batch<<16) | ((unsigned)o<<12);
  __shared__ float2 lds[4096];
  __shared__ float sh[672];
  float2 a[4];
  { // load layout A (contiguous; issues before table build)
    unsigned base = hi | ((unsigned)t<<2);
    float4 re = *(const float4*)(xre + base);
    float4 im = *(const float4*)(xim + base);
    a[0]=F2(re.x,im.x); a[1]=F2(re.y,im.y); a[2]=F2(re.z,im.z); a[3]=F2(re.w,im.w);
  }
  if (t < 60) build_entry(sh, pp0, pp1, pp2, pp3, t);
  if (blockIdx.x == 0 && t >= 64 && t < 80) out[t - 64] = 0.f;
  __syncthreads();
  if (blockIdx.x == 0){
    for (int i = t; i < 664; i += 1024) tbl[i] = sh[i];
  }
  #define LTB(i) (sh + (i)*8)
  const float* HH = sh + 480;
  const float* CS = sh + 544;
  // ---- layout A ----
  gate4<0>(a, LTB(15)); gate4<1>(a, LTB(14));                    // L1d0 b0,b1
  lgate(a, LTB(13),1,lane); lgate(a, LTB(12),2,lane);            // b2,b3
  lgate(a, LTB(11),4,lane); lgate(a, LTB(10),8,lane);            // b4,b5
  lgate(a, LTB(9),16,lane); lgate32(a, LTB(8),lane);             // b6,b7
  const unsigned IbA = ((unsigned)o<<12) | ((unsigned)wv<<8) | ((unsigned)lane<<2);
  diagv<8,7,0,0,1u,2u>(a, HH, CS, IbA);                          // D0 (7,6)..(1,0)
  gate4<1>(a, LTB(30));                                          // L1d1 b1
  lgate(a, LTB(29),1,lane); lgate(a, LTB(28),2,lane);            // b2,b3
  lgate(a, LTB(27),4,lane); lgate(a, LTB(26),8,lane);            // b4,b5
  lgate(a, LTB(25),16,lane);                                     // b6
  diagv<25,5,0,0,1u,2u>(a, HH, CS, IbA);                         // D1 (6,5)..(2,1)
  cswap(a,2,1,lane);                                             // CNOT 3->2
  cswap(a,8,4,lane);                                             // CNOT 5->4
  // ---- exchange ----
  #pragma unroll
  for (int s=0;s<4;s++) lds[swz((t<<2)|s)] = a[s];
  __syncthreads();
  const int idxR = (wv&15) | (((lane>>4)&1)<<4) | (((lane>>5)&1)<<5)
                 | (((lane>>2)&1)<<6) | (((lane>>3)&1)<<7)
                 | ((lane&1)<<8) | (((lane>>1)&1)<<9);
  #pragma unroll
  for (int s=0;s<4;s++) a[s] = lds[swz(idxR | ((s&1)<<10) | (((s>>1)&1)<<11))];
  // ---- layout B: lane=(b8:1, b9:2, b6:4, b7:8, b4:16, b5:32) ----
  lgate(a, LTB(7),1,lane); lgate(a, LTB(6),2,lane);              // L1d0 b8,b9
  gate4<0>(a, LTB(5)); gate4<1>(a, LTB(4));                      // L1d0 b10,b11
  const unsigned IbB = ((unsigned)o<<12) | (unsigned)idxR;
  diagv<4,4,0,0,1024u,2048u>(a, HH, CS, IbB);                    // D0 (11,10)..(8,7)
  lgate(a, LTB(24),8,lane);                                      // L1d1 b7
  lgate(a, LTB(23),1,lane); lgate(a, LTB(22),2,lane);            // L1d1 b8,b9
  gate4<0>(a, LTB(21));                                          // L1d1 b10
  diagv<21,4,0,0,1024u,2048u>(a, HH, CS, IbB);                   // D1 (10,9)..(7,6)
  cswap(a,8,4,lane);                                             // CNOT 7->6
  cswap(a,2,1,lane);                                             // CNOT 9->8
  {
    unsigned sb = hi | ((unsigned)wv<<8) | ((unsigned)lane<<2);
    float4 v0, v1;
    v0.x=a[0].x; v0.y=a[0].y; v0.z=a[1].x; v0.w=a[1].y;
    v1.x=a[2].x; v1.y=a[2].y; v1.z=a[3].x; v1.w=a[3].y;
    *(float4*)(st + sb) = v0;
    *(float4*)(st + sb + 2) = v1;
  }
  #undef LTB
}

// ======== pass B: tile m: m0..m11 -> b{0,1,3,5,7,9,10,11,12,13,14,15}; outer b{2,4,6,8}
// Layout A: reg=(b10,b11); lane=(b12:1,b13:2,b14:4,b15:8,b0:16,b1:32); wave=(b3,b5,b7,b9)
// Layout B: reg=(b1,b3); lane=(b5:1,b7:2,b9:4,b11:8,b13:16,b15:32); wave=(b0,b10,b12,b14)
__global__ __launch_bounds__(1024, 4)
void k_pb(const float* __restrict__ tbl, float2* __restrict__ st, float* __restrict__ out){
  const int t = threadIdx.x, lane = t & 63, wv = t >> 6;
  const int batch = blockIdx.x >> 4, o = blockIdx.x & 15;
  __shared__ float2 lds[4096];
  __shared__ float shB[672];
  __shared__ float red[16];
  const unsigned opart = ((unsigned)(o&1)<<2) | ((unsigned)((o>>1)&1)<<4)
                       | ((unsigned)((o>>2)&1)<<6) | ((unsigned)((o>>3)&1)<<8);
  float2 a[4];
  { // gather (issues first) + table staging (overlaps), then sync
    unsigned gb = ((unsigned)batch<<16)
      | (((unsigned)(o>>3)&1)<<2) | (((unsigned)(o>>2)&1)<<4)
      | (((unsigned)(o>>1)&1)<<6) | (((unsigned)o&1)<<10)
      | (((unsigned)(wv>>3)&1)<<3) | (((unsigned)(wv>>2)&1)<<5)
      | (((unsigned)(wv>>1)&1)<<7) | (((unsigned)wv&1)<<11)
      | (((unsigned)(lane>>4)&1)<<8) | (((unsigned)(lane>>5)&1)<<9)
      | (((unsigned)lane&1)<<12) | (((unsigned)(lane>>1)&1)<<13)
      | (((unsigned)(lane>>2)&1)<<14) | (((unsigned)(lane>>3)&1)<<15);
    const float4* sp = (const float4*)(st + gb);
    float4 lo = sp[0], hi4 = sp[1];
    if (t < 664) shB[t] = tbl[t];
    a[0]=F2(lo.x,lo.y); a[1]=F2(lo.z,lo.w); a[2]=F2(hi4.x,hi4.y); a[3]=F2(hi4.z,hi4.w);
  }
  __syncthreads();
  #define TBL(i) (shB + (i)*8)
  const float* HH = shB + 480;
  const float* CS = shB + 544;
  const unsigned IbA = opart
    | (((unsigned)lane&1)<<12) | (((unsigned)(lane>>1)&1)<<13)
    | (((unsigned)(lane>>2)&1)<<14) | (((unsigned)(lane>>3)&1)<<15)
    | (((unsigned)(lane>>4)&1)<<0) | (((unsigned)(lane>>5)&1)<<1)
    | (((unsigned)wv&1)<<3) | (((unsigned)(wv>>1)&1)<<5)
    | (((unsigned)(wv>>2)&1)<<7) | (((unsigned)(wv>>3)&1)<<9);
  // ---- layout A ----
  lgate(a, TBL(3),1,lane); lgate(a, TBL(2),2,lane);              // L1d0 b12,b13
  lgate(a, TBL(1),4,lane); lgate(a, TBL(0),8,lane);              // b14,b15
  diagv<0,4,15,1,1024u,2048u>(a, HH, CS, IbA);                   // D0 k0..3,k15
  lgate(a, TBL(31),16,lane);                                     // L1d1 b0
  gate4<1>(a, TBL(20));                                          // L1d1 b11
  lgate(a, TBL(19),1,lane); lgate(a, TBL(18),2,lane);            // b12,b13
  lgate(a, TBL(17),4,lane); lgate(a, TBL(16),8,lane);            // b14,b15
  diagv<16,5,30,2,1024u,2048u>(a, HH, CS, IbA);                  // D1 k16..20,k30,k31
  cswap(a,8,4,lane);                                             // CNOT 15->14
  cswap(a,2,1,lane);                                             // CNOT 13->12
  cswap(a,32,16,lane);                                           // CNOT 1->0
  { float2 tmp=a[2]; a[2]=a[3]; a[3]=tmp; }                      // CNOT 11->10 (reg)
  // ---- exchange ----
  const int idxW = ((lane>>4)&1) | (((lane>>5)&1)<<1)
                 | ((wv&1)<<2) | (((wv>>1)&1)<<3) | (((wv>>2)&1)<<4) | (((wv>>3)&1)<<5)
                 | ((lane&1)<<8) | (((lane>>1)&1)<<9)
                 | (((lane>>2)&1)<<10) | (((lane>>3)&1)<<11);
  #pragma unroll
  for (int s=0;s<4;s++) lds[sw2(idxW | ((s&1)<<6) | (((s>>1)&1)<<7))] = a[s];
  __syncthreads();
  const int idxR = (wv&1) | (((wv>>1)&1)<<6) | (((wv>>2)&1)<<8) | (((wv>>3)&1)<<10)
                 | ((lane&1)<<3) | (((lane>>1)&1)<<4) | (((lane>>2)&1)<<5)
                 | (((lane>>3)&1)<<7) | (((lane>>4)&1)<<9) | (((lane>>5)&1)<<11);
  #pragma unroll
  for (int s=0;s<4;s++) a[s] = lds[sw2(idxR | ((s&1)<<1) | (((s>>1)&1)<<2))];
  // ---- layout B ----
  const unsigned IbB = opart
    | (((unsigned)wv&1)<<0) | (((unsigned)(wv>>1)&1)<<10)
    | (((unsigned)(wv>>2)&1)<<12) | (((unsigned)(wv>>3)&1)<<14)
    | (((unsigned)lane&1)<<5) | (((unsigned)(lane>>1)&1)<<7)
    | (((unsigned)(lane>>2)&1)<<9) | (((unsigned)(lane>>3)&1)<<11)
    | (((unsigned)(lane>>4)&1)<<13) | (((unsigned)(lane>>5)&1)<<15);
  // L2d0
  gate4<0>(a, TBL(39)); gate4<1>(a, TBL(38));
  lgate(a, TBL(37),1,lane); lgate(a, TBL(36),2,lane); lgate(a, TBL(35),4,lane);
  lgate(a, TBL(34),8,lane); lgate(a, TBL(33),16,lane); lgate32(a, TBL(32),lane);
  diagv<32,8,0,0,2u,8u>(a, HH, CS, IbB);                         // D2_0
  // L2d1
  gate4<0>(a, TBL(47)); gate4<1>(a, TBL(46));
  lgate(a, TBL(45),1,lane); lgate(a, TBL(44),2,lane); lgate(a, TBL(43),4,lane);
  lgate(a, TBL(42),8,lane); lgate(a, TBL(41),16,lane); lgate32(a, TBL(40),lane);
  diagv<40,8,0,0,2u,8u>(a, HH, CS, IbB);                         // D2_1
  // sigma2: (b15->b13),(b11->b9),(b7->b5) lane; (b3->b1) reg
  cswap(a,32,16,lane); cswap(a,8,4,lane); cswap(a,2,1,lane);
  { float2 tmp=a[2]; a[2]=a[3]; a[3]=tmp; }
  // L3d0 {b15,b11,b7,b3}
  lgate32(a, TBL(48),lane); lgate(a, TBL(49),8,lane); lgate(a, TBL(50),2,lane);
  gate4<1>(a, TBL(51));
  diagv<48,4,0,0,2u,8u>(a, HH, CS, IbB);                         // D3_0
  // L3d1
  lgate32(a, TBL(52),lane); lgate(a, TBL(53),8,lane); lgate(a, TBL(54),2,lane);
  gate4<1>(a, TBL(55));
  diagv<52,4,0,0,2u,8u>(a, HH, CS, IbB);                         // D3_1
  // sigma3: (b15->b11) lane; (b7->b3): ctrl lane bit1, tgt reg s1
  cswap(a,32,8,lane);
  if (lane & 2){
    float2 t0=a[0]; a[0]=a[2]; a[2]=t0;
    float2 t1=a[1]; a[1]=a[3]; a[3]=t1;
  }
  // L4d0 {b15,b7}, D4_0, L4d1 b15
  lgate32(a, TBL(56),lane); lgate(a, TBL(57),2,lane);
  diagv<56,2,0,0,2u,8u>(a, HH, CS, IbB);
  lgate32(a, TBL(58),lane);
  // measure Z on b15 = lane bit5
  float sl = 0.f;
  #pragma unroll
  for (int s=0;s<4;s++) sl += a[s].x*a[s].x + a[s].y*a[s].y;
  float sg = (lane & 32) ? -sl : sl;
  #pragma unroll
  for (int off=32; off>0; off>>=1) sg += __shfl_down(sg, off);
  if ((t & 63) == 0) red[wv] = sg;
  __syncthreads();
  if (t == 0){
    float tot = 0.f;
    #pragma unroll
    for (int w=0; w<16; w++) tot += red[w];
    atomicAdd(out + batch, tot);
  }
  #undef TBL
}

extern "C" void kernel_launch(void* const* d_in, const int* in_sizes, int n_in,
                              void* d_out, int out_size, void* d_ws, size_t ws_size,
                              hipStream_t stream) {
  const float* xre = (const float*)d_in[0];
  const float* xim = (const float*)d_in[1];
  const float* p0  = (const float*)d_in[2];
  const float* p1  = (const float*)d_in[3];
  const float* p2  = (const float*)d_in[4];
  const float* p3  = (const float*)d_in[5];
  float* out = (float*)d_out;
  float2* st = (float2*)d_ws;                           // 8 MB state
  float* tbl = (float*)((char*)d_ws + (8u<<20));        // 664-float gate table

  k_pa<<<256, 1024, 0, stream>>>(xre, xim, p0, p1, p2, p3, tbl, st, out);
  k_pb<<<256, 1024, 0, stream>>>(tbl, st, out);
}